// Round 6
// baseline (617.678 us; speedup 1.0000x reference)
//
#include <hip/hip_runtime.h>
#include <hip/hip_fp16.h>

#define NN 50000
#define NE 800000
#define NG 128
#define IND 5
#define HID 64
#define EPSV 1e-5f
#define SCAN_T 1024

// ---- fused degree accumulate + dst histogram ----
__global__ void k_deg_hist(const int* __restrict__ dst, const float* __restrict__ w,
                           float* deg, int* hist) {
    int e = blockIdx.x * blockDim.x + threadIdx.x;
    if (e < NE) {
        int d = dst[e];
        atomicAdd(&deg[d], w[e]);
        atomicAdd(&hist[d + 1], 1);
    }
}

// deg was zero-init; self-loop adds 1 -> dinv = rsqrt(deg+1)
__global__ void k_dinv(float* deg) {
    int i = blockIdx.x * blockDim.x + threadIdx.x;
    if (i < NN) deg[i] = rsqrtf(deg[i] + 1.0f);
}

// ---- single-block inclusive scan of row_ptr[0..NN] ----
__global__ void k_scan(int* __restrict__ row_ptr) {
    __shared__ int tot[SCAN_T];
    int t = threadIdx.x;
    const int CH = (NN + 1 + SCAN_T - 1) / SCAN_T;
    int beg = t * CH;
    int end = beg + CH; if (end > NN + 1) end = NN + 1;
    int s = 0;
    for (int i = beg; i < end; i++) s += row_ptr[i];
    tot[t] = s;
    __syncthreads();
    for (int off = 1; off < SCAN_T; off <<= 1) {
        int v = (t >= off) ? tot[t - off] : 0;
        __syncthreads();
        tot[t] += v;
        __syncthreads();
    }
    int run = (t > 0) ? tot[t - 1] : 0;
    for (int i = beg; i < end; i++) { run += row_ptr[i]; row_ptr[i] = run; }
}

// ---- bin edges into CSR (src + fused norm), keyed by dst ----
__global__ void k_fill(const int* __restrict__ src, const int* __restrict__ dst,
                       const float* __restrict__ ew, const float* __restrict__ dinv,
                       const int* __restrict__ row_ptr, int* cursor, int2* __restrict__ csr) {
    int e = blockIdx.x * blockDim.x + threadIdx.x;
    if (e >= NE) return;
    int s = src[e], d = dst[e];
    int pos = row_ptr[d] + atomicAdd(&cursor[d], 1);
    float norm = dinv[s] * ew[e] * dinv[d];
    csr[pos] = make_int2(s, __float_as_int(norm));
}

// ---- pad x (N x 5) into px (N x 8, zero-padded) for aligned float4 gathers ----
__global__ void k_pad_x(const float* __restrict__ x, float* __restrict__ px) {
    int n = blockIdx.x * blockDim.x + threadIdx.x;
    if (n >= NN) return;
    float4 a, b;
    a.x = x[n * IND + 0]; a.y = x[n * IND + 1]; a.z = x[n * IND + 2]; a.w = x[n * IND + 3];
    b.x = x[n * IND + 4]; b.y = 0.f; b.z = 0.f; b.w = 0.f;
    ((float4*)px)[n * 2 + 0] = a;
    ((float4*)px)[n * 2 + 1] = b;
}

// ---- layer-1 aggregation on RAW x (aggregate-then-project), 16 lanes/node,
//      one edge per lane (stride 16), csr prefetched one step ahead. ----
__global__ void k_gather_x(const float* __restrict__ px, const float* __restrict__ dinv,
                           const int* __restrict__ row_ptr, const int2* __restrict__ csr,
                           float* __restrict__ xa) {
    int gid = blockIdx.x * blockDim.x + threadIdx.x;  // NN*16 threads
    if (gid >= NN * 16) return;
    int n = gid >> 4, lane16 = gid & 15;
    const float4* p4 = (const float4*)px;
    int beg = row_ptr[n], end = row_ptr[n + 1];
    float4 a0 = make_float4(0.f, 0.f, 0.f, 0.f);
    float a4 = 0.f;
    int i = beg + lane16;
    if (i < end) {
        int2 cur = csr[i];
        for (; i < end; i += 16) {
            int pi = (i + 16 < end) ? i + 16 : i;
            int2 nxt = csr[pi];                 // independent, overlaps h wait
            float w = __int_as_float(cur.y);
            float4 v0 = p4[cur.x * 2 + 0];
            float  v4 = px[cur.x * 8 + 4];
            a0.x += w * v0.x; a0.y += w * v0.y; a0.z += w * v0.z; a0.w += w * v0.w;
            a4 += w * v4;
            cur = nxt;
        }
    }
#pragma unroll
    for (int m = 8; m >= 1; m >>= 1) {
        a0.x += __shfl_xor(a0.x, m); a0.y += __shfl_xor(a0.y, m);
        a0.z += __shfl_xor(a0.z, m); a0.w += __shfl_xor(a0.w, m);
        a4 += __shfl_xor(a4, m);
    }
    if (lane16 == 0) {
        float di = dinv[n];
        float coef = di * di;
        float4 v0 = p4[n * 2 + 0];
        float  v4 = px[n * 8 + 4];
        float4 o0;
        o0.x = a0.x + coef * v0.x; o0.y = a0.y + coef * v0.y;
        o0.z = a0.z + coef * v0.z; o0.w = a0.w + coef * v0.w;
        ((float4*)xa)[n * 2 + 0] = o0;
        ((float4*)xa)[n * 2 + 1] = make_float4(a4 + coef * v4, 0.f, 0.f, 0.f);
    }
}

// ---- fused projection + bias + bn1 + relu:  out = relu(bn1(xa @ W1 + b1)) ----
__global__ void k_gemm1_fused(const float* __restrict__ xa, const float* __restrict__ W1,
                              const float* __restrict__ b1,
                              const float* __restrict__ gamma, const float* __restrict__ beta,
                              const float* __restrict__ mean, const float* __restrict__ var,
                              float* __restrict__ outv) {
    __shared__ float Ws[IND * HID];
    for (int j = threadIdx.x; j < IND * HID; j += blockDim.x) Ws[j] = W1[j];
    __syncthreads();
    int gid = blockIdx.x * blockDim.x + threadIdx.x;
    if (gid >= NN * HID) return;
    int n = gid >> 6, hc = gid & 63;
    const float* xr = &xa[n * 8];
    float acc = b1[hc];
#pragma unroll
    for (int k = 0; k < IND; k++) acc += xr[k] * Ws[k * HID + hc];
    float r = fmaxf((acc - mean[hc]) * rsqrtf(var[hc] + EPSV) * gamma[hc] + beta[hc], 0.f);
    outv[gid] = r;
}

// ---- a @ W2, output compressed to fp16 (gather table: 6.4 MB instead of 12.8) ----
__global__ void k_gemm2_h16(const float* __restrict__ a, const float* __restrict__ W,
                            __half* __restrict__ out) {
    __shared__ float Ws[HID * HID];
    for (int j = threadIdx.x; j < HID * HID; j += blockDim.x) Ws[j] = W[j];
    __syncthreads();
    int gid = blockIdx.x * blockDim.x + threadIdx.x;
    if (gid >= NN * HID) return;
    int n = gid >> 6, hc = gid & 63;
    const float* ar = &a[n * HID];
    float acc = 0.f;
#pragma unroll 8
    for (int k = 0; k < HID; k++) acc += ar[k] * Ws[k * HID + hc];
    out[gid] = __float2half(acc);
}

// ---- layer-2 aggregation: 8 lanes/node, 16 B/lane (uint4 = 8 halfs), 2-deep
//      edge unroll -> per wave: 8 independent chains x 2 loads in flight (4x the
//      MLP of the 16-lane serial loop, which was latency-bound at VALUBusy 3%).
//      Epilogue: self-loop + bias + bn2 + relu + pool atomics. ----
__global__ void k_gather_w(const __half* __restrict__ h16, const float* __restrict__ dinv,
                           const int* __restrict__ row_ptr, const int2* __restrict__ csr,
                           const float* __restrict__ bias,
                           const float* __restrict__ gamma, const float* __restrict__ beta,
                           const float* __restrict__ mean, const float* __restrict__ var,
                           const int* __restrict__ batch,
                           float* pool, float* cnt) {
    int gid = blockIdx.x * blockDim.x + threadIdx.x;  // NN*8 threads
    if (gid >= NN * 8) return;
    int n = gid >> 3, l8 = gid & 7;          // lane owns 8 consecutive channels
    const uint4* hq = (const uint4*)h16;     // 8 uint4 (16 B) per 64-wide row
    int beg = row_ptr[n], end = row_ptr[n + 1];

    float acc[8];
    // self-loop term issues early, overlaps edge loop
    {
        float di = dinv[n];
        float coef = di * di;
        uint4 sraw = hq[n * 8 + l8];
        float2 s0 = __half22float2(*(const __half2*)&sraw.x);
        float2 s1 = __half22float2(*(const __half2*)&sraw.y);
        float2 s2 = __half22float2(*(const __half2*)&sraw.z);
        float2 s3 = __half22float2(*(const __half2*)&sraw.w);
        acc[0] = coef * s0.x; acc[1] = coef * s0.y;
        acc[2] = coef * s1.x; acc[3] = coef * s1.y;
        acc[4] = coef * s2.x; acc[5] = coef * s2.y;
        acc[6] = coef * s3.x; acc[7] = coef * s3.y;
    }

    int i = beg;
    int2 e0, e1;
    if (i < end) e0 = csr[i];
    e1 = (i + 1 < end) ? csr[i + 1] : make_int2(0, 0);
    for (; i + 2 <= end; i += 2) {
        int2 p0 = (i + 2 < end) ? csr[i + 2] : e0;   // prefetch next pair
        int2 p1 = (i + 3 < end) ? csr[i + 3] : e1;
        uint4 r0 = hq[e0.x * 8 + l8];                // two independent loads
        uint4 r1 = hq[e1.x * 8 + l8];
        float w0 = __int_as_float(e0.y);
        float w1 = __int_as_float(e1.y);
        float2 f;
        f = __half22float2(*(const __half2*)&r0.x); acc[0] += w0 * f.x; acc[1] += w0 * f.y;
        f = __half22float2(*(const __half2*)&r0.y); acc[2] += w0 * f.x; acc[3] += w0 * f.y;
        f = __half22float2(*(const __half2*)&r0.z); acc[4] += w0 * f.x; acc[5] += w0 * f.y;
        f = __half22float2(*(const __half2*)&r0.w); acc[6] += w0 * f.x; acc[7] += w0 * f.y;
        f = __half22float2(*(const __half2*)&r1.x); acc[0] += w1 * f.x; acc[1] += w1 * f.y;
        f = __half22float2(*(const __half2*)&r1.y); acc[2] += w1 * f.x; acc[3] += w1 * f.y;
        f = __half22float2(*(const __half2*)&r1.z); acc[4] += w1 * f.x; acc[5] += w1 * f.y;
        f = __half22float2(*(const __half2*)&r1.w); acc[6] += w1 * f.x; acc[7] += w1 * f.y;
        e0 = p0; e1 = p1;
    }
    if (i < end) {                                   // odd remainder (e0 = csr[i])
        uint4 r0 = hq[e0.x * 8 + l8];
        float w0 = __int_as_float(e0.y);
        float2 f;
        f = __half22float2(*(const __half2*)&r0.x); acc[0] += w0 * f.x; acc[1] += w0 * f.y;
        f = __half22float2(*(const __half2*)&r0.y); acc[2] += w0 * f.x; acc[3] += w0 * f.y;
        f = __half22float2(*(const __half2*)&r0.z); acc[4] += w0 * f.x; acc[5] += w0 * f.y;
        f = __half22float2(*(const __half2*)&r0.w); acc[6] += w0 * f.x; acc[7] += w0 * f.y;
    }

    int c0 = l8 * 8;
    int g = batch[n];
    float bb = 0.f;  // bias folded per-channel below
    float* pp = &pool[g * HID + c0];
#pragma unroll
    for (int j = 0; j < 8; j++) {
        float v = acc[j] + bias[c0 + j];
        float r = fmaxf((v - mean[c0 + j]) * rsqrtf(var[c0 + j] + EPSV) * gamma[c0 + j] + beta[c0 + j], 0.f);
        atomicAdd(pp + j, r);
    }
    (void)bb;
    if (l8 == 0) atomicAdd(&cnt[g], 1.0f);
}

// ---------------- final MLP ----------------
__global__ void k_mlp(const float* __restrict__ pool_sums, const float* __restrict__ cnt,
                      const float* __restrict__ l1W, const float* __restrict__ l1b,
                      const float* __restrict__ l2W, const float* __restrict__ l2b,
                      float* __restrict__ outp) {
    int g = blockIdx.x * blockDim.x + threadIdx.x;
    if (g >= NG) return;
    float c = fmaxf(cnt[g], 1.0f);
    float inv = 1.0f / c;
    float p[HID];
#pragma unroll
    for (int k = 0; k < HID; k++) p[k] = pool_sums[g * HID + k] * inv;
    float acc = 0.f;
    for (int j = 0; j < HID / 2; j++) {
        float z = l1b[j];
#pragma unroll 8
        for (int k = 0; k < HID; k++) z += p[k] * l1W[k * (HID / 2) + j];
        acc += fmaxf(z, 0.f) * l2W[j];
    }
    outp[g] = acc + l2b[0];
}

extern "C" void kernel_launch(void* const* d_in, const int* in_sizes, int n_in,
                              void* d_out, int out_size, void* d_ws, size_t ws_size,
                              hipStream_t stream) {
    const float* x   = (const float*)d_in[0];
    const int*   ei  = (const int*)d_in[1];
    const float* ew  = (const float*)d_in[2];
    const int*   bat = (const int*)d_in[3];
    const float* W1  = (const float*)d_in[4];
    const float* b1  = (const float*)d_in[5];
    const float* W2  = (const float*)d_in[6];
    const float* b2  = (const float*)d_in[7];
    const float* g1  = (const float*)d_in[8];
    const float* be1 = (const float*)d_in[9];
    const float* m1  = (const float*)d_in[10];
    const float* v1  = (const float*)d_in[11];
    const float* g2  = (const float*)d_in[12];
    const float* be2 = (const float*)d_in[13];
    const float* m2  = (const float*)d_in[14];
    const float* v2  = (const float*)d_in[15];
    const float* l1W = (const float*)d_in[16];
    const float* l1b = (const float*)d_in[17];
    const float* l2W = (const float*)d_in[18];
    const float* l2b = (const float*)d_in[19];
    float* out = (float*)d_out;

    const int* src = ei;
    const int* dst = ei + NE;

    // ---- workspace layout (4-byte units) ----
    float* f = (float*)d_ws;
    float* dinv    = f + 0;               // 50000 (zeroed -> rsqrt(deg+1))
    float* pool    = f + 50000;           // 8192
    float* cnt     = f + 58192;           // 128
    int*   row_ptr = (int*)(f + 58320);   // 50001
    int*   cursor  = (int*)(f + 108321);  // 50000
    // zero region = [0, 158321) floats
    int2*  csr     = (int2*)(f + 158336); // 800000 int2 -> ends 1758336
    float* px      = f + 1758336;         // NN*8
    float* xa      = f + 2158336;         // NN*8
    float* bufC    = f + 2558336;         // NN*HID fp32 (layer-1 activated)
    __half* h16    = (__half*)(f + 5758336); // NN*HID fp16 (layer-2 gather table)
    // total = 7358336 floats = 29.4 MB

    const int BLK = 256;
    const int gN   = (NN + BLK - 1) / BLK;
    const int gE   = (NE + BLK - 1) / BLK;
    const int gNH  = (NN * HID + BLK - 1) / BLK;
    const int gN16 = (NN * 16 + BLK - 1) / BLK;
    const int gN8  = (NN * 8 + BLK - 1) / BLK;

    hipMemsetAsync(d_ws, 0, 158321 * sizeof(float), stream);

    // normalization + CSR build (shared across both conv layers)
    k_deg_hist<<<gE, BLK, 0, stream>>>(dst, ew, dinv, row_ptr);
    k_dinv<<<gN, BLK, 0, stream>>>(dinv);
    k_scan<<<1, SCAN_T, 0, stream>>>(row_ptr);
    k_fill<<<gE, BLK, 0, stream>>>(src, dst, ew, dinv, row_ptr, cursor, csr);

    // layer 1: aggregate raw x (5-wide) then project (+bias+bn1+relu fused)
    k_pad_x<<<gN, BLK, 0, stream>>>(x, px);
    k_gather_x<<<gN16, BLK, 0, stream>>>(px, dinv, row_ptr, csr, xa);
    k_gemm1_fused<<<gNH, BLK, 0, stream>>>(xa, W1, b1, g1, be1, m1, v1, bufC);

    // layer 2: project to fp16, gather (+bias+bn2+relu+pool fused)
    k_gemm2_h16<<<gNH, BLK, 0, stream>>>(bufC, W2, h16);
    k_gather_w<<<gN8, BLK, 0, stream>>>(h16, dinv, row_ptr, csr, b2,
                                        g2, be2, m2, v2, bat, pool, cnt);

    // MLP head
    k_mlp<<<1, 128, 0, stream>>>(pool, cnt, l1W, l1b, l2W, l2b, out);
}

// Round 7
// 528.859 us; speedup vs baseline: 1.1679x; 1.1679x over previous
//
#include <hip/hip_runtime.h>
#include <hip/hip_fp16.h>

#define NN 50000
#define NE 800000
#define NG 128
#define IND 5
#define HID 64
#define EPSV 1e-5f
#define SCAN_T 1024

// ---- dst histogram (counts at d+1) ----
__global__ void k_hist(const int* __restrict__ dst, int* row_ptr) {
    int e = blockIdx.x * blockDim.x + threadIdx.x;
    if (e < NE) atomicAdd(&row_ptr[dst[e] + 1], 1);
}

// ---- single-block inclusive scan of row_ptr[0..NN] ----
__global__ void k_scan(int* __restrict__ row_ptr) {
    __shared__ int tot[SCAN_T];
    int t = threadIdx.x;
    const int CH = (NN + 1 + SCAN_T - 1) / SCAN_T;
    int beg = t * CH;
    int end = beg + CH; if (end > NN + 1) end = NN + 1;
    int s = 0;
    for (int i = beg; i < end; i++) s += row_ptr[i];
    tot[t] = s;
    __syncthreads();
    for (int off = 1; off < SCAN_T; off <<= 1) {
        int v = (t >= off) ? tot[t - off] : 0;
        __syncthreads();
        tot[t] += v;
        __syncthreads();
    }
    int run = (t > 0) ? tot[t - 1] : 0;
    for (int i = beg; i < end; i++) { run += row_ptr[i]; row_ptr[i] = run; }
}

// ---- bin edges into CSR as (src, raw w) — NO dinv dependency ----
__global__ void k_fill_w(const int* __restrict__ src, const int* __restrict__ dst,
                         const float* __restrict__ ew,
                         const int* __restrict__ row_ptr, int* cursor, int2* __restrict__ csr) {
    int e = blockIdx.x * blockDim.x + threadIdx.x;
    if (e >= NE) return;
    int s = src[e], d = dst[e];
    int pos = row_ptr[d] + atomicAdd(&cursor[d], 1);
    csr[pos] = make_int2(s, __float_as_int(ew[e]));
}

// ---- deg from CSR rows (sequential, no atomics): dinv = rsqrt(sum(w)+1) ----
__global__ void k_deg_dinv(const int* __restrict__ row_ptr, const int2* __restrict__ csr,
                           float* __restrict__ dinv) {
    int gid = blockIdx.x * blockDim.x + threadIdx.x;  // NN*4 threads
    if (gid >= NN * 4) return;
    int n = gid >> 2, l = gid & 3;
    int beg = row_ptr[n], end = row_ptr[n + 1];
    float s = 0.f;
    for (int i = beg + l; i < end; i += 4) s += __int_as_float(csr[i].y);
    s += __shfl_xor(s, 1);
    s += __shfl_xor(s, 2);
    if (l == 0) dinv[n] = rsqrtf(s + 1.0f);
}

// ---- px = dinv[n] * x[n], padded 5 -> 8 ----
__global__ void k_pad_scale_x(const float* __restrict__ x, const float* __restrict__ dinv,
                              float* __restrict__ px) {
    int n = blockIdx.x * blockDim.x + threadIdx.x;
    if (n >= NN) return;
    float di = dinv[n];
    float4 a, b;
    a.x = di * x[n * IND + 0]; a.y = di * x[n * IND + 1];
    a.z = di * x[n * IND + 2]; a.w = di * x[n * IND + 3];
    b.x = di * x[n * IND + 4]; b.y = 0.f; b.z = 0.f; b.w = 0.f;
    ((float4*)px)[n * 2 + 0] = a;
    ((float4*)px)[n * 2 + 1] = b;
}

// ---- layer-1 aggregation on pre-scaled raw x:  xa[d] = dinv_d*(sum w*px[s] + px[d]) ----
__global__ void k_gather_x(const float* __restrict__ px, const float* __restrict__ dinv,
                           const int* __restrict__ row_ptr, const int2* __restrict__ csr,
                           float* __restrict__ xa) {
    int gid = blockIdx.x * blockDim.x + threadIdx.x;  // NN*16 threads
    if (gid >= NN * 16) return;
    int n = gid >> 4, lane16 = gid & 15;
    const float4* p4 = (const float4*)px;
    int beg = row_ptr[n], end = row_ptr[n + 1];
    float4 a0 = make_float4(0.f, 0.f, 0.f, 0.f);
    float a4 = 0.f;
    int i = beg + lane16;
    if (i < end) {
        long long cur = __builtin_nontemporal_load((const long long*)&csr[i]);
        for (; i < end; i += 16) {
            int pi = (i + 16 < end) ? i + 16 : i;
            long long nxt = __builtin_nontemporal_load((const long long*)&csr[pi]);
            int   s = (int)(cur & 0xffffffffLL);
            float w = __int_as_float((int)(cur >> 32));
            float4 v0 = p4[s * 2 + 0];
            float  v4 = px[s * 8 + 4];
            a0.x += w * v0.x; a0.y += w * v0.y; a0.z += w * v0.z; a0.w += w * v0.w;
            a4 += w * v4;
            cur = nxt;
        }
    }
#pragma unroll
    for (int m = 8; m >= 1; m >>= 1) {
        a0.x += __shfl_xor(a0.x, m); a0.y += __shfl_xor(a0.y, m);
        a0.z += __shfl_xor(a0.z, m); a0.w += __shfl_xor(a0.w, m);
        a4 += __shfl_xor(a4, m);
    }
    if (lane16 == 0) {
        float di = dinv[n];
        float4 v0 = p4[n * 2 + 0];
        float  v4 = px[n * 8 + 4];
        float4 o0;
        o0.x = di * (a0.x + v0.x); o0.y = di * (a0.y + v0.y);
        o0.z = di * (a0.z + v0.z); o0.w = di * (a0.w + v0.w);
        ((float4*)xa)[n * 2 + 0] = o0;
        ((float4*)xa)[n * 2 + 1] = make_float4(di * (a4 + v4), 0.f, 0.f, 0.f);
    }
}

// ---- fused projection + bias + bn1 + relu ----
__global__ void k_gemm1_fused(const float* __restrict__ xa, const float* __restrict__ W1,
                              const float* __restrict__ b1,
                              const float* __restrict__ gamma, const float* __restrict__ beta,
                              const float* __restrict__ mean, const float* __restrict__ var,
                              float* __restrict__ outv) {
    __shared__ float Ws[IND * HID];
    for (int j = threadIdx.x; j < IND * HID; j += blockDim.x) Ws[j] = W1[j];
    __syncthreads();
    int gid = blockIdx.x * blockDim.x + threadIdx.x;
    if (gid >= NN * HID) return;
    int n = gid >> 6, hc = gid & 63;
    const float* xr = &xa[n * 8];
    float acc = b1[hc];
#pragma unroll
    for (int k = 0; k < IND; k++) acc += xr[k] * Ws[k * HID + hc];
    float r = fmaxf((acc - mean[hc]) * rsqrtf(var[hc] + EPSV) * gamma[hc] + beta[hc], 0.f);
    outv[gid] = r;
}

// ---- a @ W2, pre-scaled by dinv[n], output column-split into two fp16 tables
//      (3.2 MB each -> per-XCD-L2 resident for the gather passes) ----
__global__ void k_gemm2_h16(const float* __restrict__ a, const float* __restrict__ W,
                            const float* __restrict__ dinv,
                            __half* __restrict__ tabA, __half* __restrict__ tabB) {
    __shared__ float Ws[HID * HID];
    for (int j = threadIdx.x; j < HID * HID; j += blockDim.x) Ws[j] = W[j];
    __syncthreads();
    int gid = blockIdx.x * blockDim.x + threadIdx.x;
    if (gid >= NN * HID) return;
    int n = gid >> 6, hc = gid & 63;
    const float* ar = &a[n * HID];
    float acc = 0.f;
#pragma unroll 8
    for (int k = 0; k < HID; k++) acc += ar[k] * Ws[k * HID + hc];
    __half v = __float2half(dinv[n] * acc);
    if (hc < 32) tabA[n * 32 + hc] = v;
    else         tabB[n * 32 + (hc - 32)] = v;
}

// ---- layer-2 gather over ONE 3.2MB half-table (32 channels), 8 lanes/node,
//      uint2 (4 halfs)/lane, serial edge loop with 1-ahead nontemporal csr
//      prefetch.  out = dinv_d*(sum w*tab[s] + tab[d]) + b2 -> bn2 -> relu
//      -> pool atomics (4 per lane, R5-proven count). ----
template <int HALF>
__global__ void k_gather_half(const __half* __restrict__ tab, const float* __restrict__ dinv,
                              const int* __restrict__ row_ptr, const int2* __restrict__ csr,
                              const float* __restrict__ bias,
                              const float* __restrict__ gamma, const float* __restrict__ beta,
                              const float* __restrict__ mean, const float* __restrict__ var,
                              const int* __restrict__ batch,
                              float* pool, float* cnt) {
    int gid = blockIdx.x * blockDim.x + threadIdx.x;  // NN*8 threads
    if (gid >= NN * 8) return;
    int n = gid >> 3, l8 = gid & 7;
    const uint2* hq = (const uint2*)tab;   // 8 uint2 per 32-ch row
    int beg = row_ptr[n], end = row_ptr[n + 1];

    // self row (already dinv_n-scaled)
    uint2 sraw = hq[n * 8 + l8];
    float2 s0 = __half22float2(*(const __half2*)&sraw.x);
    float2 s1 = __half22float2(*(const __half2*)&sraw.y);
    float a0 = s0.x, a1 = s0.y, a2 = s1.x, a3 = s1.y;

    if (beg < end) {
        long long cur = __builtin_nontemporal_load((const long long*)&csr[beg]);
        for (int i = beg; i < end; i++) {
            int pi = (i + 1 < end) ? i + 1 : i;
            long long nxt = __builtin_nontemporal_load((const long long*)&csr[pi]);
            int   s = (int)(cur & 0xffffffffLL);
            float w = __int_as_float((int)(cur >> 32));
            uint2 raw = hq[s * 8 + l8];
            float2 f0 = __half22float2(*(const __half2*)&raw.x);
            float2 f1 = __half22float2(*(const __half2*)&raw.y);
            a0 += w * f0.x; a1 += w * f0.y;
            a2 += w * f1.x; a3 += w * f1.y;
            cur = nxt;
        }
    }

    float di = dinv[n];
    int c0 = HALF * 32 + l8 * 4;
    int g = batch[n];
    float* pp = &pool[g * HID + c0];
    float vals[4] = {a0, a1, a2, a3};
#pragma unroll
    for (int j = 0; j < 4; j++) {
        float v = di * vals[j] + bias[c0 + j];
        float r = fmaxf((v - mean[c0 + j]) * rsqrtf(var[c0 + j] + EPSV) * gamma[c0 + j] + beta[c0 + j], 0.f);
        atomicAdd(pp + j, r);
    }
    if (HALF == 0 && l8 == 0) atomicAdd(&cnt[g], 1.0f);
}

// ---------------- final MLP ----------------
__global__ void k_mlp(const float* __restrict__ pool_sums, const float* __restrict__ cnt,
                      const float* __restrict__ l1W, const float* __restrict__ l1b,
                      const float* __restrict__ l2W, const float* __restrict__ l2b,
                      float* __restrict__ outp) {
    int g = blockIdx.x * blockDim.x + threadIdx.x;
    if (g >= NG) return;
    float c = fmaxf(cnt[g], 1.0f);
    float inv = 1.0f / c;
    float p[HID];
#pragma unroll
    for (int k = 0; k < HID; k++) p[k] = pool_sums[g * HID + k] * inv;
    float acc = 0.f;
    for (int j = 0; j < HID / 2; j++) {
        float z = l1b[j];
#pragma unroll 8
        for (int k = 0; k < HID; k++) z += p[k] * l1W[k * (HID / 2) + j];
        acc += fmaxf(z, 0.f) * l2W[j];
    }
    outp[g] = acc + l2b[0];
}

extern "C" void kernel_launch(void* const* d_in, const int* in_sizes, int n_in,
                              void* d_out, int out_size, void* d_ws, size_t ws_size,
                              hipStream_t stream) {
    const float* x   = (const float*)d_in[0];
    const int*   ei  = (const int*)d_in[1];
    const float* ew  = (const float*)d_in[2];
    const int*   bat = (const int*)d_in[3];
    const float* W1  = (const float*)d_in[4];
    const float* b1  = (const float*)d_in[5];
    const float* W2  = (const float*)d_in[6];
    const float* b2  = (const float*)d_in[7];
    const float* g1  = (const float*)d_in[8];
    const float* be1 = (const float*)d_in[9];
    const float* m1  = (const float*)d_in[10];
    const float* v1  = (const float*)d_in[11];
    const float* g2  = (const float*)d_in[12];
    const float* be2 = (const float*)d_in[13];
    const float* m2  = (const float*)d_in[14];
    const float* v2  = (const float*)d_in[15];
    const float* l1W = (const float*)d_in[16];
    const float* l1b = (const float*)d_in[17];
    const float* l2W = (const float*)d_in[18];
    const float* l2b = (const float*)d_in[19];
    float* out = (float*)d_out;

    const int* src = ei;
    const int* dst = ei + NE;

    // ---- workspace layout (4-byte units) ----
    float* f = (float*)d_ws;
    float* pool    = f + 0;               // 8192
    float* cnt     = f + 8192;            // 128
    int*   row_ptr = (int*)(f + 8320);    // 50001
    int*   cursor  = (int*)(f + 58321);   // 50000
    // zero region = [0, 108321) floats
    int2*  csr     = (int2*)(f + 108328); // 800000 int2 (8B aligned) -> ends 1708328
    float* dinv    = f + 1708328;         // 50000
    float* px      = f + 1758328;         // NN*8
    float* xa      = f + 2158328;         // NN*8
    float* bufC    = f + 2558328;         // NN*HID fp32
    __half* tabA   = (__half*)(f + 5758328); // NN*32 fp16 (3.2 MB)
    __half* tabB   = (__half*)(f + 6558328); // NN*32 fp16 (3.2 MB)
    // total = 7358328 floats = 29.4 MB

    const int BLK = 256;
    const int gN   = (NN + BLK - 1) / BLK;
    const int gE   = (NE + BLK - 1) / BLK;
    const int gNH  = (NN * HID + BLK - 1) / BLK;
    const int gN16 = (NN * 16 + BLK - 1) / BLK;
    const int gN8  = (NN * 8 + BLK - 1) / BLK;
    const int gN4  = (NN * 4 + BLK - 1) / BLK;

    hipMemsetAsync(d_ws, 0, 108321 * sizeof(float), stream);

    // CSR build (dinv-free), then degree/dinv from CSR rows
    k_hist<<<gE, BLK, 0, stream>>>(dst, row_ptr);
    k_scan<<<1, SCAN_T, 0, stream>>>(row_ptr);
    k_fill_w<<<gE, BLK, 0, stream>>>(src, dst, ew, row_ptr, cursor, csr);
    k_deg_dinv<<<gN4, BLK, 0, stream>>>(row_ptr, csr, dinv);

    // layer 1: pre-scaled raw-x aggregation, then project (+bias+bn1+relu fused)
    k_pad_scale_x<<<gN, BLK, 0, stream>>>(x, dinv, px);
    k_gather_x<<<gN16, BLK, 0, stream>>>(px, dinv, row_ptr, csr, xa);
    k_gemm1_fused<<<gNH, BLK, 0, stream>>>(xa, W1, b1, g1, be1, m1, v1, bufC);

    // layer 2: project to pre-scaled fp16 split tables, two L2-resident gather passes
    k_gemm2_h16<<<gNH, BLK, 0, stream>>>(bufC, W2, dinv, tabA, tabB);
    k_gather_half<0><<<gN8, BLK, 0, stream>>>(tabA, dinv, row_ptr, csr, b2,
                                              g2, be2, m2, v2, bat, pool, cnt);
    k_gather_half<1><<<gN8, BLK, 0, stream>>>(tabB, dinv, row_ptr, csr, b2,
                                              g2, be2, m2, v2, bat, pool, cnt);

    // MLP head
    k_mlp<<<1, 128, 0, stream>>>(pool, cnt, l1W, l1b, l2W, l2b, out);
}